// Round 4
// baseline (157.067 us; speedup 1.0000x reference)
//
#include <hip/hip_runtime.h>

// (B,C,H,W) = (4,64,64,64) -> N=4096, Cr=8. Single-head attn, d_k=8, d_v=64.
#define BB 4
#define CC 64
#define NN 4096

typedef __attribute__((ext_vector_type(8))) short short8;
typedef __attribute__((ext_vector_type(4))) float f32x4;
typedef unsigned short u16;

// workspace (all bf16): qws [B*N][8], kws [B*N][8], vws [B*64][N] (V transposed)
#define QWS_ELEMS (BB * NN * 8)

__device__ inline u16 f2bf(float x) {
    unsigned u = __float_as_uint(x);
    u = (u + 0x7fffu + ((u >> 16) & 1u)) >> 16;   // RNE
    return (u16)u;
}
__device__ inline unsigned pack2rne(float a, float b) {
    return (unsigned)f2bf(a) | ((unsigned)f2bf(b) << 16);
}
// truncating bf16 pack of two floats in one v_perm_b32 (used for P only)
__device__ inline unsigned permpack(float lo, float hi) {
    return __builtin_amdgcn_perm(__float_as_uint(hi), __float_as_uint(lo), 0x07060302);
}

// ---------------------------------------------------------------------------
// Kernel 1: QKV projection. Block = 64 pixels x 4 waves. Wave w = "part"
// (forced wave-uniform via readfirstlane -> weights become SGPR scalar
// loads). part0: q[0..8)+k[0..8)+v[60..64); part p>=1: v[20(p-1)..20p).
// x read once per part (4x total, L2-resident). All outputs bf16.
// ---------------------------------------------------------------------------
__global__ __launch_bounds__(256) void proj_kernel(
    const float* __restrict__ x,
    const float* __restrict__ wq, const float* __restrict__ bq,
    const float* __restrict__ wk, const float* __restrict__ bk,
    const float* __restrict__ wv, const float* __restrict__ bv,
    u16* __restrict__ ws_u)
{
    u16* qws = ws_u;
    u16* kws = ws_u + QWS_ELEMS;
    u16* vws = ws_u + 2 * QWS_ELEMS;

    const int part = __builtin_amdgcn_readfirstlane(threadIdx.x >> 6);
    const int pix  = blockIdx.x * 64 + (threadIdx.x & 63);
    const int b    = pix >> 12;
    const int n    = pix & (NN - 1);
    const float* xb = x + ((size_t)b << 18) + n;

    float xr[CC];
#pragma unroll
    for (int c = 0; c < CC; ++c) xr[c] = xb[(size_t)c << 12];   // coalesced

    if (part == 0) {
        float aq[8], ak[8], av[4];
#pragma unroll
        for (int i = 0; i < 8; ++i) { aq[i] = bq[i]; ak[i] = bk[i]; }
#pragma unroll
        for (int i = 0; i < 4; ++i) av[i] = bv[60 + i];
#pragma unroll
        for (int c = 0; c < CC; ++c) {
            const float xv = xr[c];
#pragma unroll
            for (int i = 0; i < 8; ++i) {
                aq[i] += wq[i * CC + c] * xv;    // scalar (uniform) loads
                ak[i] += wk[i * CC + c] * xv;
            }
#pragma unroll
            for (int i = 0; i < 4; ++i)
                av[i] += wv[(60 + i) * CC + c] * xv;
        }
        uint4 qp, kp;
        qp.x = pack2rne(aq[0], aq[1]); qp.y = pack2rne(aq[2], aq[3]);
        qp.z = pack2rne(aq[4], aq[5]); qp.w = pack2rne(aq[6], aq[7]);
        kp.x = pack2rne(ak[0], ak[1]); kp.y = pack2rne(ak[2], ak[3]);
        kp.z = pack2rne(ak[4], ak[5]); kp.w = pack2rne(ak[6], ak[7]);
        *(uint4*)&qws[(size_t)pix * 8] = qp;    // 16B/lane, coalesced
        *(uint4*)&kws[(size_t)pix * 8] = kp;
#pragma unroll
        for (int i = 0; i < 4; ++i)
            vws[(((size_t)((b << 6) + 60 + i)) << 12) + n] = f2bf(av[i]);
    } else {
        const int o0 = (part - 1) * 20;
        float av[20];
#pragma unroll
        for (int i = 0; i < 20; ++i) av[i] = bv[o0 + i];
#pragma unroll
        for (int c = 0; c < CC; ++c) {
            const float xv = xr[c];
#pragma unroll
            for (int i = 0; i < 20; ++i)
                av[i] += wv[(o0 + i) * CC + c] * xv;
        }
#pragma unroll
        for (int i = 0; i < 20; ++i)
            vws[(((size_t)((b << 6) + o0 + i)) << 12) + n] = f2bf(av[i]);
    }
}

// ---------------------------------------------------------------------------
// Kernel 2: fused MFMA flash attention, V fragments loaded DIRECTLY from
// global (L2-resident; B-frag's 8-consecutive-m per lane is contiguous in
// vws[c][m]). LDS holds only the P round-trip (double-buffered, swizzled:
// elem (row,m) at row*64 + ((m>>3 ^ (row&7))<<3) + (m&7)).
// Block: 512 thr (8 waves), 64 queries, 64-key tiles, 1 barrier/tile.
// S-duty wave w: m-chunk mc=w>>1, q-half qh=w&1 (2 tiles).
// PV-duty wave w: q-chunk qc=w&3, c-half ch=w>>2 (4 MFMAs, 2 acc).
// ---------------------------------------------------------------------------
__global__ __launch_bounds__(512) void attn_kernel(
    const float* __restrict__ x, const float* __restrict__ gamma,
    const u16* __restrict__ ws_u, float* __restrict__ out)
{
    const u16* qws = ws_u;
    const u16* kws = ws_u + QWS_ELEMS;
    const u16* vws = ws_u + 2 * QWS_ELEMS;

    __shared__ u16   p_t[2][64 * 64];   // 8 KB per buffer
    __shared__ float l_sh[8][32];

    const int tid  = threadIdx.x;
    const int w    = tid >> 6;
    const int lane = tid & 63;
    const int quad = lane >> 4;
    const int l15  = lane & 15;

    const int b  = blockIdx.y;
    const int qb = blockIdx.x << 6;    // 64 queries/block
    const int bN = b << 12;

    // ---- S duty ----
    const int mc = w >> 1;
    const int qh = w & 1;

    short8 qf0 = {0,0,0,0,0,0,0,0}, qf1 = {0,0,0,0,0,0,0,0};
    short8 kf  = {0,0,0,0,0,0,0,0};
    if (quad == 0) {   // quads 1-3 hold k>=8 (all zero)
        qf0 = *(const short8*)(qws + (size_t)(bN + qb + (qh << 5) + l15) * 8);
        qf1 = *(const short8*)(qws + (size_t)(bN + qb + (qh << 5) + 16 + l15) * 8);
        kf  = *(const short8*)(kws + (size_t)(bN + (mc << 4) + l15) * 8);
    }

    // P write offsets (tile t row = qh*32 + t*16 + l15; both share sw=l15&7)
    const int sw   = l15 & 7;
    const int pm8  = (mc << 1) + (quad >> 1);
    const int poff = (quad & 1) << 2;
    const int pw0  = ((qh << 5) + l15) * 64 + ((pm8 ^ sw) << 3) + poff;
    const int pw1  = pw0 + (16 * 64);

    // ---- PV duty ----
    const int qc   = w & 3;
    const int ch   = w >> 2;
    const int prow = (qc << 4) + l15;
    const int pr0  = prow * 64 + ((quad ^ sw) << 3);         // k-chunk 0
    const int pr1  = prow * 64 + (((4 + quad) ^ sw) << 3);   // k-chunk 1

    // V fragment base pointers (c rows for this wave's two c-chunks)
    const u16* vp0 = vws + (((size_t)((b << 6) + ((ch << 1) + 0) * 16 + l15)) << 12) + (quad << 3);
    const u16* vp1 = vws + (((size_t)((b << 6) + ((ch << 1) + 1) * 16 + l15)) << 12) + (quad << 3);

    // prefetch V frags for tile 0 (kc0 at +0, kc1 at +32)
    short8 vf00 = *(const short8*)(vp0);
    short8 vf01 = *(const short8*)(vp1);
    short8 vf10 = *(const short8*)(vp0 + 32);
    short8 vf11 = *(const short8*)(vp1 + 32);

    f32x4 acc0 = {0.f, 0.f, 0.f, 0.f};
    f32x4 acc1 = {0.f, 0.f, 0.f, 0.f};
    float ls0 = 0.f, ls1 = 0.f;

    for (int it = 0; it < 64; ++it) {
        const int buf   = it & 1;
        const int mnext = ((it + 1) & 63) << 6;   // wrap: harmless warm read

        // S^T tiles (m-chunk mc x q-chunks 2qh, 2qh+1)
        f32x4 s0 = __builtin_amdgcn_mfma_f32_16x16x32_bf16(
            kf, qf0, (f32x4){0.f,0.f,0.f,0.f}, 0, 0, 0);
        f32x4 s1 = __builtin_amdgcn_mfma_f32_16x16x32_bf16(
            kf, qf1, (f32x4){0.f,0.f,0.f,0.f}, 0, 0, 0);
        if (quad == 0)
            kf = *(const short8*)(kws + (size_t)(bN + mnext + (mc << 4) + l15) * 8);

        const float p00 = __expf(s0[0]), p01 = __expf(s0[1]);
        const float p02 = __expf(s0[2]), p03 = __expf(s0[3]);
        const float p10 = __expf(s1[0]), p11 = __expf(s1[1]);
        const float p12 = __expf(s1[2]), p13 = __expf(s1[3]);
        ls0 += (p00 + p01) + (p02 + p03);
        ls1 += (p10 + p11) + (p12 + p13);
        uint2 a0, a1;
        a0.x = permpack(p00, p01); a0.y = permpack(p02, p03);
        a1.x = permpack(p10, p11); a1.y = permpack(p12, p13);
        *(uint2*)&p_t[buf][pw0] = a0;
        *(uint2*)&p_t[buf][pw1] = a1;

        __syncthreads();   // only barrier per tile (p_t double-buffered)

        const short8 pf0 = *(const short8*)&p_t[buf][pr0];
        const short8 pf1 = *(const short8*)&p_t[buf][pr1];
        acc0 = __builtin_amdgcn_mfma_f32_16x16x32_bf16(pf0, vf00, acc0, 0, 0, 0);
        acc1 = __builtin_amdgcn_mfma_f32_16x16x32_bf16(pf0, vf01, acc1, 0, 0, 0);
        acc0 = __builtin_amdgcn_mfma_f32_16x16x32_bf16(pf1, vf10, acc0, 0, 0, 0);
        acc1 = __builtin_amdgcn_mfma_f32_16x16x32_bf16(pf1, vf11, acc1, 0, 0, 0);

        // prefetch next tile's V frags (used after NEXT barrier -> covered)
        vf00 = *(const short8*)(vp0 + mnext);
        vf01 = *(const short8*)(vp1 + mnext);
        vf10 = *(const short8*)(vp0 + mnext + 32);
        vf11 = *(const short8*)(vp1 + mnext + 32);
    }

    // softmax denominators: quads hold disjoint m within tile -> butterfly,
    // then combine the 4 m-chunks (held by waves 2mc+qh) via LDS.
    ls0 += __shfl_xor(ls0, 16, 64); ls0 += __shfl_xor(ls0, 32, 64);
    ls1 += __shfl_xor(ls1, 16, 64); ls1 += __shfl_xor(ls1, 32, 64);
    if (quad == 0) { l_sh[w][l15] = ls0; l_sh[w][16 + l15] = ls1; }
    __syncthreads();

    const int qhh = qc >> 1;               // which l_sh q-half
    const int qq0 = ((qc & 1) << 4) + (quad << 2);
    float rl[4];
#pragma unroll
    for (int r = 0; r < 4; ++r)
        rl[r] = 1.f / (l_sh[0 + qhh][qq0 + r] + l_sh[2 + qhh][qq0 + r] +
                       l_sh[4 + qhh][qq0 + r] + l_sh[6 + qhh][qq0 + r]);

    const float g = gamma[0];
#pragma unroll
    for (int j = 0; j < 2; ++j) {
        const int c = ((ch << 1) + j) * 16 + l15;
        const f32x4 a = j ? acc1 : acc0;
        const size_t base = (((size_t)((b << 6) + c)) << 12) + qb + (qc << 4) + (quad << 2);
        const float4 xv = *(const float4*)&x[base];
        float4 o;
        o.x = xv.x + g * a[0] * rl[0];
        o.y = xv.y + g * a[1] * rl[1];
        o.z = xv.z + g * a[2] * rl[2];
        o.w = xv.w + g * a[3] * rl[3];
        *(float4*)&out[base] = o;
    }
}

// ---------------------------------------------------------------------------
extern "C" void kernel_launch(void* const* d_in, const int* in_sizes, int n_in,
                              void* d_out, int out_size, void* d_ws, size_t ws_size,
                              hipStream_t stream)
{
    const float* x     = (const float*)d_in[0];
    const float* wq    = (const float*)d_in[1];
    const float* bq    = (const float*)d_in[2];
    const float* wk    = (const float*)d_in[3];
    const float* bk    = (const float*)d_in[4];
    const float* wv    = (const float*)d_in[5];
    const float* bv    = (const float*)d_in[6];
    const float* gamma = (const float*)d_in[7];
    u16*   ws  = (u16*)d_ws;
    float* out = (float*)d_out;

    hipLaunchKernelGGL(proj_kernel, dim3(BB * NN / 64), dim3(256), 0, stream,
                       x, wq, bq, wk, bk, wv, bv, ws);
    hipLaunchKernelGGL(attn_kernel, dim3(NN / 64, BB), dim3(512), 0, stream,
                       x, gamma, ws, out);
}

// Round 6
// 106.754 us; speedup vs baseline: 1.4713x; 1.4713x over previous
//
#include <hip/hip_runtime.h>

// (B,C,H,W) = (4,64,64,64) -> N=4096, Cr=8. Single-head attn, d_k=8, d_v=64.
#define BB 4
#define CC 64
#define NN 4096

typedef __attribute__((ext_vector_type(8)))  short short8;
typedef __attribute__((ext_vector_type(4)))  short short4v;
typedef __attribute__((ext_vector_type(4)))  float f32x4;
typedef __attribute__((ext_vector_type(16))) float f32x16;
typedef unsigned short u16;

// workspace (all bf16): qws [B*N][8], kws [B*N][8], vws [B*64][N] (V transposed)
#define QWS_ELEMS (BB * NN * 8)

__device__ inline u16 f2bf(float x) {
    unsigned u = __float_as_uint(x);
    u = (u + 0x7fffu + ((u >> 16) & 1u)) >> 16;   // RNE
    return (u16)u;
}
__device__ inline unsigned pack2rne(float a, float b) {
    return (unsigned)f2bf(a) | ((unsigned)f2bf(b) << 16);
}
// truncating bf16 pack of two floats in one v_perm_b32 (P only; 6x error headroom)
__device__ inline unsigned permpack(float lo, float hi) {
    return __builtin_amdgcn_perm(__float_as_uint(hi), __float_as_uint(lo), 0x07060302);
}

union SH8 {
    short8 s;
    struct Halves { short4v lo, hi; } h;
    uint4 u;
};

// ---------------------------------------------------------------------------
// Kernel 1: QKV projection, 4-way output split in blockIdx.y (block-uniform ->
// scalar weight loads). y0: q[0..8)+v[0..12); y1: k[0..8)+v[12..24);
// y2: v[24..44); y3: v[44..64). Grid (64,4) = 256 blocks x 256 thr.
// ---------------------------------------------------------------------------
__global__ __launch_bounds__(256) void proj_kernel(
    const float* __restrict__ x,
    const float* __restrict__ wq, const float* __restrict__ bq,
    const float* __restrict__ wk, const float* __restrict__ bk,
    const float* __restrict__ wv, const float* __restrict__ bv,
    u16* __restrict__ ws_u)
{
    u16* qws = ws_u;
    u16* kws = ws_u + QWS_ELEMS;
    u16* vws = ws_u + 2 * QWS_ELEMS;

    const int y   = blockIdx.y;                    // 0..3, block-uniform
    const int pix = blockIdx.x * 256 + threadIdx.x;
    const int b   = pix >> 12;
    const int n   = pix & (NN - 1);
    const float* xb = x + ((size_t)b << 18) + n;

    float xr[CC];
#pragma unroll
    for (int c = 0; c < CC; ++c) xr[c] = xb[(size_t)c << 12];   // coalesced 256B segs

    if (y <= 1) {
        const float* wp = (y == 0) ? wq : wk;
        const float* bp = (y == 0) ? bq : bk;
        const int v0 = y * 12;
        float a8[8], av[12];
#pragma unroll
        for (int i = 0; i < 8; ++i)  a8[i] = bp[i];
#pragma unroll
        for (int i = 0; i < 12; ++i) av[i] = bv[v0 + i];
#pragma unroll 4
        for (int c = 0; c < CC; ++c) {
            const float xv = xr[c];
#pragma unroll
            for (int i = 0; i < 8; ++i)  a8[i] += wp[i * CC + c] * xv;  // scalar loads
#pragma unroll
            for (int i = 0; i < 12; ++i) av[i] += wv[(v0 + i) * CC + c] * xv;
        }
        uint4 p4;
        p4.x = pack2rne(a8[0], a8[1]); p4.y = pack2rne(a8[2], a8[3]);
        p4.z = pack2rne(a8[4], a8[5]); p4.w = pack2rne(a8[6], a8[7]);
        u16* dst = (y == 0) ? qws : kws;
        *(uint4*)&dst[(size_t)pix * 8] = p4;       // 16B/lane coalesced
#pragma unroll
        for (int i = 0; i < 12; ++i)
            vws[(((size_t)((b << 6) + v0 + i)) << 12) + n] = f2bf(av[i]);
    } else {
        const int v0 = 24 + (y - 2) * 20;
        float av[20];
#pragma unroll
        for (int i = 0; i < 20; ++i) av[i] = bv[v0 + i];
#pragma unroll 4
        for (int c = 0; c < CC; ++c) {
            const float xv = xr[c];
#pragma unroll
            for (int i = 0; i < 20; ++i) av[i] += wv[(v0 + i) * CC + c] * xv;
        }
#pragma unroll
        for (int i = 0; i < 20; ++i)
            vws[(((size_t)((b << 6) + v0 + i)) << 12) + n] = f2bf(av[i]);
    }
}

// ---------------------------------------------------------------------------
// Kernel 2: fused 32x32x16-MFMA flash attention. Block 512 thr (8 waves =
// 4 m-chunks x 2 q-halves), 64 q/block, 128-key tiles, 32 iters, ONE barrier
// per iter. S^T = K*Q^T per wave (32m x 32q, K=16 w/ 8 real ch). The exp'd
// S D-fragment is repacked IN-REGISTER into the PV A-fragment using a
// permuted k-slot order; V's B-fragments are gathered from LDS with the SAME
// permutation (2x ds_read_b64 per frag). P never touches LDS. V is staged
// global->LDS double-buffered (rows padded to 132 u16 -> uniform bank use).
// Per-wave PV partials (own m-chunk) are tree-reduced over mh at the end.
// ---------------------------------------------------------------------------
__global__ __launch_bounds__(512) void attn_kernel(
    const float* __restrict__ x, const float* __restrict__ gamma,
    const u16* __restrict__ ws_u, float* __restrict__ out)
{
    const u16* qws = ws_u;
    const u16* kws = ws_u + QWS_ELEMS;
    const u16* vws = ws_u + 2 * QWS_ELEMS;

    // smem: region A = v_t [2][64*132] u16 (33792 B) ALIASED with
    // eb [8][64*17] f32 (34816 B, used only after the K-loop), then l_part,
    // l_inv. Total 36.1 KB.
    __shared__ __align__(16) char smem[34816 + 1024 + 256];
    u16*   v_t    = (u16*)smem;                    // [2][64*132]
    float* eb     = (float*)smem;                  // [8][64*17]
    float* l_part = (float*)(smem + 34816);        // [8][32]
    float* l_inv  = (float*)(smem + 34816 + 1024); // [2][32]

    const int tid  = threadIdx.x;
    const int w    = tid >> 6;
    const int lane = tid & 63;
    const int l31  = lane & 31;
    const int lh   = lane >> 5;
    const int mh   = w >> 1;       // 0..3 m-chunk
    const int qh   = w & 1;        // 0..1 q-half

    const int b  = blockIdx.y;
    const int qb = blockIdx.x << 6;   // 64 queries/block
    const int bN = b << 12;

    // S fragments (lanes>=32 supply k-slots 8..15 = zero; only 8 real ch)
    short8 qf = {0,0,0,0,0,0,0,0};
    short8 kf = {0,0,0,0,0,0,0,0};
    if (lane < 32) {
        qf = *(const short8*)(qws + (size_t)(bN + qb + (qh << 5) + l31) * 8);
        kf = *(const short8*)(kws + (size_t)(bN + (mh << 5) + l31) * 8);
    }

    // V staging: thread -> (row c_st, octets o_st, o_st+64) of the 128-m tile
    const int c_st = tid >> 3;
    const int o_st = (tid & 7) << 3;                 // u16 offset of octet
    const u16* vgr = vws + (((size_t)((b << 6) + c_st)) << 12) + o_st;
    const int st0  = c_st * 132 + o_st;              // 132-u16 padded rows

    SH8 va0, va1, vb0, vb1;
    va0.s = *(const short8*)(vgr);                   // tile 0
    va1.s = *(const short8*)(vgr + 64);
    *(short4v*)&v_t[st0]      = va0.h.lo;            // b64 writes (8B-aligned)
    *(short4v*)&v_t[st0 + 4]  = va0.h.hi;
    *(short4v*)&v_t[st0 + 64] = va1.h.lo;
    *(short4v*)&v_t[st0 + 68] = va1.h.hi;
    va0.s = *(const short8*)(vgr + 128);             // tile 1 -> regs
    va1.s = *(const short8*)(vgr + 192);

    // PV read geometry: row c = (ch*32 + l31); b64 pair at (mb, mb+8) for ks0
    // and (mb+16, mb+24) for ks1, where mb = mh*32 + lh*4 (slot permutation).
    const int rA = l31 * 132;          // ch0 rows
    const int rB = (32 + l31) * 132;   // ch1 rows
    const int mb = (mh << 5) + (lh << 2);

    f32x16 z16, acc0, acc1;
#pragma unroll
    for (int r = 0; r < 16; ++r) { z16[r] = 0.f; acc0[r] = 0.f; acc1[r] = 0.f; }
    float ls = 0.f;

    __syncthreads();

#pragma unroll 2
    for (int it = 0; it < 32; ++it) {
        const int buf = (it & 1) * (CC * 132);
        const int nxt = ((it + 1) & 31) << 7;        // *128 (wrap: warm read)
        const int nx2 = ((it + 2) & 31) << 7;

        // S^T tile: D[m][q], lane: q=l31, 16 m in regs
        f32x16 d = __builtin_amdgcn_mfma_f32_32x32x16_bf16(kf, qf, z16, 0, 0, 0);

        // issue next-K and tile+2 V global loads EARLY (covered by exp+PV
        // before the barrier's vmcnt drain)
        if (lane < 32)
            kf = *(const short8*)(kws + (size_t)(bN + nxt + (mh << 5) + l31) * 8);
        vb0.s = *(const short8*)(vgr + nx2);
        vb1.s = *(const short8*)(vgr + nx2 + 64);

        float p[16];
#pragma unroll
        for (int r = 0; r < 16; ++r) p[r] = __expf(d[r]);
        float s0 = 0.f, s1 = 0.f;
#pragma unroll
        for (int r = 0; r < 8; ++r) { s0 += p[2 * r]; s1 += p[2 * r + 1]; }
        ls += s0 + s1;

        // in-register D->A repack (slot order = native reg order per lane)
        SH8 A0, A1;
        A0.u.x = permpack(p[0],  p[1]);  A0.u.y = permpack(p[2],  p[3]);
        A0.u.z = permpack(p[4],  p[5]);  A0.u.w = permpack(p[6],  p[7]);
        A1.u.x = permpack(p[8],  p[9]);  A1.u.y = permpack(p[10], p[11]);
        A1.u.z = permpack(p[12], p[13]); A1.u.w = permpack(p[14], p[15]);

        // V B-frags with matching slot permutation (2x b64 each)
        SH8 B00, B01, B10, B11;
        B00.h.lo = *(const short4v*)&v_t[buf + rA + mb];
        B00.h.hi = *(const short4v*)&v_t[buf + rA + mb + 8];
        B01.h.lo = *(const short4v*)&v_t[buf + rB + mb];
        B01.h.hi = *(const short4v*)&v_t[buf + rB + mb + 8];
        B10.h.lo = *(const short4v*)&v_t[buf + rA + mb + 16];
        B10.h.hi = *(const short4v*)&v_t[buf + rA + mb + 24];
        B11.h.lo = *(const short4v*)&v_t[buf + rB + mb + 16];
        B11.h.hi = *(const short4v*)&v_t[buf + rB + mb + 24];

        acc0 = __builtin_amdgcn_mfma_f32_32x32x16_bf16(A0.s, B00.s, acc0, 0, 0, 0);
        acc1 = __builtin_amdgcn_mfma_f32_32x32x16_bf16(A0.s, B01.s, acc1, 0, 0, 0);
        acc0 = __builtin_amdgcn_mfma_f32_32x32x16_bf16(A1.s, B10.s, acc0, 0, 0, 0);
        acc1 = __builtin_amdgcn_mfma_f32_32x32x16_bf16(A1.s, B11.s, acc1, 0, 0, 0);

        // stage tile t+1 into the other buffer (safe: all waves passed the
        // previous barrier, so nobody still reads it)
        const int ob = (CC * 132) - buf;             // the other buffer
        *(short4v*)&v_t[ob + st0]      = va0.h.lo;
        *(short4v*)&v_t[ob + st0 + 4]  = va0.h.hi;
        *(short4v*)&v_t[ob + st0 + 64] = va1.h.lo;
        *(short4v*)&v_t[ob + st0 + 68] = va1.h.hi;
        va0 = vb0; va1 = vb1;

        __syncthreads();   // only barrier per 128-key tile
    }

    // softmax denominators: lane pair (l, l+32) share q=l31, disjoint m
    float lt = ls + __shfl_xor(ls, 32, 64);
    if (lane < 32) l_part[(mh * 2 + qh) * 32 + l31] = lt;
    __syncthreads();       // also retires last v_t use before eb aliasing
    if (w < 2 && lane < 32) {
        float s = l_part[(0 * 2 + qh) * 32 + l31] + l_part[(1 * 2 + qh) * 32 + l31]
                + l_part[(2 * 2 + qh) * 32 + l31] + l_part[(3 * 2 + qh) * 32 + l31];
        l_inv[qh * 32 + l31] = 1.0f / s;
    }

    // tree-reduce acc over the 4 m-chunks (blobs are opaque [lane][reg] dumps)
    if (mh >= 2) {
        float* e0 = &eb[(((mh - 2) << 2) + (qh << 1) + 0) * 1088 + lane * 17];
        float* e1 = &eb[(((mh - 2) << 2) + (qh << 1) + 1) * 1088 + lane * 17];
#pragma unroll
        for (int r = 0; r < 16; ++r) { e0[r] = acc0[r]; e1[r] = acc1[r]; }
    }
    __syncthreads();
    if (mh < 2) {
        const float* e0 = &eb[((mh << 2) + (qh << 1) + 0) * 1088 + lane * 17];
        const float* e1 = &eb[((mh << 2) + (qh << 1) + 1) * 1088 + lane * 17];
#pragma unroll
        for (int r = 0; r < 16; ++r) { acc0[r] += e0[r]; acc1[r] += e1[r]; }
    }
    __syncthreads();
    if (mh == 1) {
        float* e0 = &eb[((qh << 1) + 0) * 1088 + lane * 17];
        float* e1 = &eb[((qh << 1) + 1) * 1088 + lane * 17];
#pragma unroll
        for (int r = 0; r < 16; ++r) { e0[r] = acc0[r]; e1[r] = acc1[r]; }
    }
    __syncthreads();
    if (w < 2) {
        const float* e0 = &eb[((qh << 1) + 0) * 1088 + lane * 17];
        const float* e1 = &eb[((qh << 1) + 1) * 1088 + lane * 17];
#pragma unroll
        for (int r = 0; r < 16; ++r) { acc0[r] += e0[r]; acc1[r] += e1[r]; }

        // D rows: q = 8k + 4*lh + (r&3) for regs 4k..4k+3; col c = l31 (+32)
        f32x4 li[4];
#pragma unroll
        for (int k = 0; k < 4; ++k)
            li[k] = *(const f32x4*)&l_inv[qh * 32 + (k << 3) + (lh << 2)];
        const float g = gamma[0];
#pragma unroll
        for (int ch = 0; ch < 2; ++ch) {
            const int c = (ch << 5) + l31;
            const f32x16 a = ch ? acc1 : acc0;
            const size_t rowb = (((size_t)((b << 6) + c)) << 12) + qb + (qh << 5);
#pragma unroll
            for (int k = 0; k < 4; ++k) {
                const int q0 = (k << 3) + (lh << 2);
                const float4 xv = *(const float4*)&x[rowb + q0];
                float4 o;
                o.x = xv.x + g * a[4 * k + 0] * li[k][0];
                o.y = xv.y + g * a[4 * k + 1] * li[k][1];
                o.z = xv.z + g * a[4 * k + 2] * li[k][2];
                o.w = xv.w + g * a[4 * k + 3] * li[k][3];
                *(float4*)&out[rowb + q0] = o;
            }
        }
    }
}

// ---------------------------------------------------------------------------
extern "C" void kernel_launch(void* const* d_in, const int* in_sizes, int n_in,
                              void* d_out, int out_size, void* d_ws, size_t ws_size,
                              hipStream_t stream)
{
    const float* x     = (const float*)d_in[0];
    const float* wq    = (const float*)d_in[1];
    const float* bq    = (const float*)d_in[2];
    const float* wk    = (const float*)d_in[3];
    const float* bk    = (const float*)d_in[4];
    const float* wv    = (const float*)d_in[5];
    const float* bv    = (const float*)d_in[6];
    const float* gamma = (const float*)d_in[7];
    u16*   ws  = (u16*)d_ws;
    float* out = (float*)d_out;

    hipLaunchKernelGGL(proj_kernel, dim3(BB * NN / 256, 4), dim3(256), 0, stream,
                       x, wq, bq, wk, bk, wv, bv, ws);
    hipLaunchKernelGGL(attn_kernel, dim3(NN / 64, BB), dim3(512), 0, stream,
                       x, gamma, ws, out);
}

// Round 7
// 105.867 us; speedup vs baseline: 1.4836x; 1.0084x over previous
//
#include <hip/hip_runtime.h>

// (B,C,H,W) = (4,64,64,64) -> N=4096, Cr=8. Single-head attn, d_k=8, d_v=64.
#define BB 4
#define CC 64
#define NN 4096

typedef __attribute__((ext_vector_type(8)))  short short8;
typedef __attribute__((ext_vector_type(4)))  short short4v;
typedef __attribute__((ext_vector_type(4)))  float f32x4;
typedef __attribute__((ext_vector_type(16))) float f32x16;
typedef unsigned short u16;

// workspace (all bf16): qws [B*N][8], kws [B*N][8], vws [B*64][N] (V transposed)
#define QWS_ELEMS (BB * NN * 8)

__device__ inline u16 f2bf(float x) {
    unsigned u = __float_as_uint(x);
    u = (u + 0x7fffu + ((u >> 16) & 1u)) >> 16;   // RNE
    return (u16)u;
}
__device__ inline unsigned pack2rne(float a, float b) {
    return (unsigned)f2bf(a) | ((unsigned)f2bf(b) << 16);
}
// truncating bf16 pack of two floats in one v_perm_b32 (P only; 6x error headroom)
__device__ inline unsigned permpack(float lo, float hi) {
    return __builtin_amdgcn_perm(__float_as_uint(hi), __float_as_uint(lo), 0x07060302);
}

// Barrier with LDS-only drain: does NOT wait vmcnt, so global prefetches
// stay in flight across the barrier (correctness needs only ds ordering:
// staging ds_writes and fragment ds_reads both retire via lgkmcnt).
__device__ inline void barrier_lgkm() {
    asm volatile("s_waitcnt lgkmcnt(0)\n\ts_barrier" ::: "memory");
}

union SH8 {
    short8 s;
    struct Halves { short4v lo, hi; } h;
    uint4 u;
};

// ---------------------------------------------------------------------------
// Kernel 1: QKV projection. Grid (32, 9) x 512 thr, 1 pixel/thread.
// blockIdx.y picks a block-uniform output slice (-> SGPR weight loads):
// y<8: v[8y..8y+8) (512 FMA/thr); y==8: q[0..8)+k[0..8) (1024 FMA/thr).
// Streaming form: one coalesced x load per channel feeding 8-16 FMAs.
// 288 blocks -> >=1 block (8 waves) per CU for latency hiding.
// ---------------------------------------------------------------------------
__global__ __launch_bounds__(512) void proj_kernel(
    const float* __restrict__ x,
    const float* __restrict__ wq, const float* __restrict__ bq,
    const float* __restrict__ wk, const float* __restrict__ bk,
    const float* __restrict__ wv, const float* __restrict__ bv,
    u16* __restrict__ ws_u)
{
    u16* qws = ws_u;
    u16* kws = ws_u + QWS_ELEMS;
    u16* vws = ws_u + 2 * QWS_ELEMS;

    const int y   = blockIdx.y;                    // 0..8, block-uniform
    const int pix = blockIdx.x * 512 + threadIdx.x;
    const int b   = pix >> 12;
    const int n   = pix & (NN - 1);
    const float* xb = x + ((size_t)b << 18) + n;

    if (y < 8) {
        const int v0 = y << 3;
        float av[8];
#pragma unroll
        for (int i = 0; i < 8; ++i) av[i] = bv[v0 + i];
#pragma unroll 8
        for (int c = 0; c < CC; ++c) {
            const float xv = xb[(size_t)c << 12];          // coalesced 256B/wave
#pragma unroll
            for (int i = 0; i < 8; ++i)
                av[i] += wv[(v0 + i) * CC + c] * xv;       // scalar (uniform) loads
        }
#pragma unroll
        for (int i = 0; i < 8; ++i)
            vws[(((size_t)((b << 6) + v0 + i)) << 12) + n] = f2bf(av[i]);
    } else {
        float aq[8], ak[8];
#pragma unroll
        for (int i = 0; i < 8; ++i) { aq[i] = bq[i]; ak[i] = bk[i]; }
#pragma unroll 8
        for (int c = 0; c < CC; ++c) {
            const float xv = xb[(size_t)c << 12];
#pragma unroll
            for (int i = 0; i < 8; ++i) {
                aq[i] += wq[i * CC + c] * xv;
                ak[i] += wk[i * CC + c] * xv;
            }
        }
        uint4 qp, kp;
        qp.x = pack2rne(aq[0], aq[1]); qp.y = pack2rne(aq[2], aq[3]);
        qp.z = pack2rne(aq[4], aq[5]); qp.w = pack2rne(aq[6], aq[7]);
        kp.x = pack2rne(ak[0], ak[1]); kp.y = pack2rne(ak[2], ak[3]);
        kp.z = pack2rne(ak[4], ak[5]); kp.w = pack2rne(ak[6], ak[7]);
        *(uint4*)&qws[(size_t)pix * 8] = qp;               // 16B/lane coalesced
        *(uint4*)&kws[(size_t)pix * 8] = kp;
    }
}

// ---------------------------------------------------------------------------
// Kernel 2: fused 32x32x16-MFMA flash attention. Block 512 thr (8 waves =
// 4 m-chunks x 2 q-halves), 64 q/block, 128-key tiles, 32 iters, ONE
// lgkm-only barrier per iter (global prefetches never drained). S^T = K*Q^T
// per wave; exp'd S D-frag repacked IN-REGISTER to the PV A-frag via a
// permuted k-slot order; V B-frags gathered from LDS with the SAME
// permutation (2x ds_read_b64 each). P never touches LDS. V staged
// global->LDS double-buffered (132-u16 padded rows). Prefetches issued at
// top-of-iter for max in-flight span. Per-wave PV partials tree-reduced.
// ---------------------------------------------------------------------------
__global__ __launch_bounds__(512) void attn_kernel(
    const float* __restrict__ x, const float* __restrict__ gamma,
    const u16* __restrict__ ws_u, float* __restrict__ out)
{
    const u16* qws = ws_u;
    const u16* kws = ws_u + QWS_ELEMS;
    const u16* vws = ws_u + 2 * QWS_ELEMS;

    // smem: v_t [2][64*132] u16 (33792 B) ALIASED with eb [8][64*17] f32
    // (34816 B, used only after the K-loop), then l_part, l_inv.
    __shared__ __align__(16) char smem[34816 + 1024 + 256];
    u16*   v_t    = (u16*)smem;                    // [2][64*132]
    float* eb     = (float*)smem;                  // [8][64*17]
    float* l_part = (float*)(smem + 34816);        // [8][32]
    float* l_inv  = (float*)(smem + 34816 + 1024); // [2][32]

    const int tid  = threadIdx.x;
    const int w    = tid >> 6;
    const int lane = tid & 63;
    const int l31  = lane & 31;
    const int lh   = lane >> 5;
    const int mh   = w >> 1;       // 0..3 m-chunk
    const int qh   = w & 1;        // 0..1 q-half

    const int b  = blockIdx.y;
    const int qb = blockIdx.x << 6;   // 64 queries/block
    const int bN = b << 12;

    // S fragments (lanes>=32 supply k-slots 8..15 = zero; only 8 real ch)
    short8 qf = {0,0,0,0,0,0,0,0};
    short8 kf = {0,0,0,0,0,0,0,0};
    if (lane < 32) {
        qf = *(const short8*)(qws + (size_t)(bN + qb + (qh << 5) + l31) * 8);
        kf = *(const short8*)(kws + (size_t)(bN + (mh << 5) + l31) * 8);
    }
    short8 kn = kf;

    // V staging: thread -> (row c_st, octets o_st, o_st+64) of the 128-m tile
    const int c_st = tid >> 3;
    const int o_st = (tid & 7) << 3;                 // u16 offset of octet
    const u16* vgr = vws + (((size_t)((b << 6) + c_st)) << 12) + o_st;
    const int st0  = c_st * 132 + o_st;              // 132-u16 padded rows

    SH8 va0, va1, vb0, vb1;
    va0.s = *(const short8*)(vgr);                   // tile 0
    va1.s = *(const short8*)(vgr + 64);
    *(short4v*)&v_t[st0]      = va0.h.lo;            // b64 writes (8B-aligned)
    *(short4v*)&v_t[st0 + 4]  = va0.h.hi;
    *(short4v*)&v_t[st0 + 64] = va1.h.lo;
    *(short4v*)&v_t[st0 + 68] = va1.h.hi;
    va0.s = *(const short8*)(vgr + 128);             // tile 1 -> regs
    va1.s = *(const short8*)(vgr + 192);

    // PV read geometry: row c = (ch*32 + l31); b64 pair at (mb, mb+8) for ks0
    // and (mb+16, mb+24) for ks1, where mb = mh*32 + lh*4 (slot permutation).
    const int rA = l31 * 132;          // ch0 rows
    const int rB = (32 + l31) * 132;   // ch1 rows
    const int mb = (mh << 5) + (lh << 2);

    f32x16 z16, acc0, acc1;
#pragma unroll
    for (int r = 0; r < 16; ++r) { z16[r] = 0.f; acc0[r] = 0.f; acc1[r] = 0.f; }
    float ls = 0.f;

    barrier_lgkm();   // tile-0 staging visible; va/tile-1 loads stay in flight

#pragma unroll 2
    for (int it = 0; it < 32; ++it) {
        const int buf = (it & 1) * (CC * 132);
        const int nxt = ((it + 1) & 31) << 7;        // *128 (wrap: warm read)
        const int nx2 = ((it + 2) & 31) << 7;

        // top-of-iter global prefetches: consumed next iter -> full-iter
        // in-flight span, never drained by the lgkm-only barrier.
        vb0.s = *(const short8*)(vgr + nx2);
        vb1.s = *(const short8*)(vgr + nx2 + 64);
        if (lane < 32)
            kn = *(const short8*)(kws + (size_t)(bN + nxt + (mh << 5) + l31) * 8);

        // S^T tile: D[m][q], lane: q=l31, 16 m in regs
        f32x16 d = __builtin_amdgcn_mfma_f32_32x32x16_bf16(kf, qf, z16, 0, 0, 0);

        float p[16];
#pragma unroll
        for (int r = 0; r < 16; ++r) p[r] = __expf(d[r]);
        float s0 = 0.f, s1 = 0.f;
#pragma unroll
        for (int r = 0; r < 8; ++r) { s0 += p[2 * r]; s1 += p[2 * r + 1]; }
        ls += s0 + s1;

        // in-register D->A repack (slot order = native reg order per lane)
        SH8 A0, A1;
        A0.u.x = permpack(p[0],  p[1]);  A0.u.y = permpack(p[2],  p[3]);
        A0.u.z = permpack(p[4],  p[5]);  A0.u.w = permpack(p[6],  p[7]);
        A1.u.x = permpack(p[8],  p[9]);  A1.u.y = permpack(p[10], p[11]);
        A1.u.z = permpack(p[12], p[13]); A1.u.w = permpack(p[14], p[15]);

        // V B-frags with matching slot permutation (2x b64 each)
        SH8 B00, B01, B10, B11;
        B00.h.lo = *(const short4v*)&v_t[buf + rA + mb];
        B00.h.hi = *(const short4v*)&v_t[buf + rA + mb + 8];
        B01.h.lo = *(const short4v*)&v_t[buf + rB + mb];
        B01.h.hi = *(const short4v*)&v_t[buf + rB + mb + 8];
        B10.h.lo = *(const short4v*)&v_t[buf + rA + mb + 16];
        B10.h.hi = *(const short4v*)&v_t[buf + rA + mb + 24];
        B11.h.lo = *(const short4v*)&v_t[buf + rB + mb + 16];
        B11.h.hi = *(const short4v*)&v_t[buf + rB + mb + 24];

        acc0 = __builtin_amdgcn_mfma_f32_32x32x16_bf16(A0.s, B00.s, acc0, 0, 0, 0);
        acc1 = __builtin_amdgcn_mfma_f32_32x32x16_bf16(A0.s, B01.s, acc1, 0, 0, 0);
        acc0 = __builtin_amdgcn_mfma_f32_32x32x16_bf16(A1.s, B10.s, acc0, 0, 0, 0);
        acc1 = __builtin_amdgcn_mfma_f32_32x32x16_bf16(A1.s, B11.s, acc1, 0, 0, 0);

        // stage tile t+1 into the other buffer (all waves passed the previous
        // barrier, so nobody still reads it)
        const int ob = (CC * 132) - buf;             // the other buffer
        *(short4v*)&v_t[ob + st0]      = va0.h.lo;
        *(short4v*)&v_t[ob + st0 + 4]  = va0.h.hi;
        *(short4v*)&v_t[ob + st0 + 64] = va1.h.lo;
        *(short4v*)&v_t[ob + st0 + 68] = va1.h.hi;
        va0 = vb0; va1 = vb1;
        kf = kn;

        barrier_lgkm();   // LDS-only drain: prefetches stay in flight
    }

    // softmax denominators: lane pair (l, l+32) share q=l31, disjoint m
    float lt = ls + __shfl_xor(ls, 32, 64);
    if (lane < 32) l_part[(mh * 2 + qh) * 32 + l31] = lt;
    __syncthreads();       // also retires last v_t use before eb aliasing
    if (w < 2 && lane < 32) {
        float s = l_part[(0 * 2 + qh) * 32 + l31] + l_part[(1 * 2 + qh) * 32 + l31]
                + l_part[(2 * 2 + qh) * 32 + l31] + l_part[(3 * 2 + qh) * 32 + l31];
        l_inv[qh * 32 + l31] = 1.0f / s;
    }

    // tree-reduce acc over the 4 m-chunks (blobs are opaque [lane][reg] dumps)
    if (mh >= 2) {
        float* e0 = &eb[(((mh - 2) << 2) + (qh << 1) + 0) * 1088 + lane * 17];
        float* e1 = &eb[(((mh - 2) << 2) + (qh << 1) + 1) * 1088 + lane * 17];
#pragma unroll
        for (int r = 0; r < 16; ++r) { e0[r] = acc0[r]; e1[r] = acc1[r]; }
    }
    __syncthreads();
    if (mh < 2) {
        const float* e0 = &eb[((mh << 2) + (qh << 1) + 0) * 1088 + lane * 17];
        const float* e1 = &eb[((mh << 2) + (qh << 1) + 1) * 1088 + lane * 17];
#pragma unroll
        for (int r = 0; r < 16; ++r) { acc0[r] += e0[r]; acc1[r] += e1[r]; }
    }
    __syncthreads();
    if (mh == 1) {
        float* e0 = &eb[((qh << 1) + 0) * 1088 + lane * 17];
        float* e1 = &eb[((qh << 1) + 1) * 1088 + lane * 17];
#pragma unroll
        for (int r = 0; r < 16; ++r) { e0[r] = acc0[r]; e1[r] = acc1[r]; }
    }
    __syncthreads();
    if (w < 2) {
        const float* e0 = &eb[((qh << 1) + 0) * 1088 + lane * 17];
        const float* e1 = &eb[((qh << 1) + 1) * 1088 + lane * 17];
#pragma unroll
        for (int r = 0; r < 16; ++r) { acc0[r] += e0[r]; acc1[r] += e1[r]; }

        // D rows: q = 8k + 4*lh + (r&3) for regs 4k..4k+3; col c = l31 (+32)
        f32x4 li[4];
#pragma unroll
        for (int k = 0; k < 4; ++k)
            li[k] = *(const f32x4*)&l_inv[qh * 32 + (k << 3) + (lh << 2)];
        const float g = gamma[0];
#pragma unroll
        for (int ch = 0; ch < 2; ++ch) {
            const int c = (ch << 5) + l31;
            const f32x16 a = ch ? acc1 : acc0;
            const size_t rowb = (((size_t)((b << 6) + c)) << 12) + qb + (qh << 5);
#pragma unroll
            for (int k = 0; k < 4; ++k) {
                const int q0 = (k << 3) + (lh << 2);
                const float4 xv = *(const float4*)&x[rowb + q0];
                float4 o;
                o.x = xv.x + g * a[4 * k + 0] * li[k][0];
                o.y = xv.y + g * a[4 * k + 1] * li[k][1];
                o.z = xv.z + g * a[4 * k + 2] * li[k][2];
                o.w = xv.w + g * a[4 * k + 3] * li[k][3];
                *(float4*)&out[rowb + q0] = o;
            }
        }
    }
}

// ---------------------------------------------------------------------------
extern "C" void kernel_launch(void* const* d_in, const int* in_sizes, int n_in,
                              void* d_out, int out_size, void* d_ws, size_t ws_size,
                              hipStream_t stream)
{
    const float* x     = (const float*)d_in[0];
    const float* wq    = (const float*)d_in[1];
    const float* bq    = (const float*)d_in[2];
    const float* wk    = (const float*)d_in[3];
    const float* bk    = (const float*)d_in[4];
    const float* wv    = (const float*)d_in[5];
    const float* bv    = (const float*)d_in[6];
    const float* gamma = (const float*)d_in[7];
    u16*   ws  = (u16*)d_ws;
    float* out = (float*)d_out;

    hipLaunchKernelGGL(proj_kernel, dim3(BB * NN / 512, 9), dim3(512), 0, stream,
                       x, wq, bq, wk, bk, wv, bv, ws);
    hipLaunchKernelGGL(attn_kernel, dim3(NN / 64, BB), dim3(512), 0, stream,
                       x, gamma, ws, out);
}